// Round 1
// baseline (2035.644 us; speedup 1.0000x reference)
//
#include <hip/hip_runtime.h>

#define NN 100000      // nodes
#define NE 1000000     // edges
#define NG 1024        // graphs
#define NSG 128        // subgraphs
#define EF 32          // edge feature dim
#define HH 64          // hidden
#define NOUT 32        // output classes
#define NL 3           // layers

// wave-uniform broadcast of lane l's value (v_readlane -> SGPR, no DS traffic)
__device__ __forceinline__ float bcastf(float v, int l) {
    return __int_as_float(__builtin_amdgcn_readlane(__float_as_int(v), l));
}

// ---------------------------------------------------------------------------
// per-graph node counts
__global__ void cnt_kernel(const int* __restrict__ batch, float* __restrict__ cnt) {
    int i = blockIdx.x * blockDim.x + threadIdx.x;
    if (i < NN) atomicAdd(&cnt[batch[i]], 1.0f);
}

// per-subgraph weight norms
__global__ void norm_kernel(const int* __restrict__ sgb, const float* __restrict__ w,
                            float* __restrict__ norm) {
    int i = blockIdx.x * blockDim.x + threadIdx.x;
    if (i < NG) atomicAdd(&norm[sgb[i]], w[i]);
}

// ---------------------------------------------------------------------------
// Edge pass: emb = relu(ea@W1+b1)@W2+b2 ; msg = relu(h[src]+emb) ; agg[dst] += msg
// One wave per edge; lane j owns output feature j; W1/W2 columns in VGPRs.
__global__ __launch_bounds__(256, 2) void edge_kernel(
    const float* __restrict__ hin,       // [NN,64]
    const float* __restrict__ eattr,     // [NE,32]
    const int*   __restrict__ eidx,      // [2,NE]
    const float* __restrict__ w1,        // [32,64] (layer slice)
    const float* __restrict__ b1,        // [64]
    const float* __restrict__ w2,        // [64,64]
    const float* __restrict__ b2,        // [64]
    float*       __restrict__ agg)       // [NN,64]
{
    const int lane   = threadIdx.x & 63;
    const int wave   = (blockIdx.x * blockDim.x + threadIdx.x) >> 6;
    const int nwaves = (gridDim.x * blockDim.x) >> 6;

    float w1c[EF];
    #pragma unroll
    for (int i = 0; i < EF; ++i) w1c[i] = w1[i * HH + lane];
    float w2c[HH];
    #pragma unroll
    for (int i = 0; i < HH; ++i) w2c[i] = w2[i * HH + lane];
    const float b1j = b1[lane];
    const float b2j = b2[lane];

    for (int e = wave; e < NE; e += nwaves) {
        const float a = eattr[e * EF + (lane & 31)];   // lanes 32-63 mirror 0-31
        float t = b1j;
        #pragma unroll
        for (int i = 0; i < EF; ++i) t = fmaf(bcastf(a, i), w1c[i], t);
        t = fmaxf(t, 0.0f);
        float emb = b2j;
        #pragma unroll
        for (int k = 0; k < HH; ++k) emb = fmaf(bcastf(t, k), w2c[k], emb);
        const int src = eidx[e];
        const int dst = eidx[NE + e];
        const float msg = fmaxf(hin[src * HH + lane] + emb, 0.0f);
        atomicAdd(&agg[dst * HH + lane], msg);
    }
}

// ---------------------------------------------------------------------------
// Node pass: z=(1+eps)*h+agg ; v=relu(relu(z@W1+b1)@W2+b2) ; v written in-place
// into agg; per-feature sum/sumsq accumulated for BN.
__global__ __launch_bounds__(256, 2) void node_kernel(
    const float* __restrict__ hin,
    float*       agg,                    // in: agg, out: v (aliased on purpose)
    const float* __restrict__ w1, const float* __restrict__ b1,
    const float* __restrict__ w2, const float* __restrict__ b2,
    const float* __restrict__ epsp,
    float*       __restrict__ stats)     // [0:64] sum, [64:128] sumsq
{
    const int lane   = threadIdx.x & 63;
    const int wave   = (blockIdx.x * blockDim.x + threadIdx.x) >> 6;
    const int nwaves = (gridDim.x * blockDim.x) >> 6;

    float w1c[HH], w2c[HH];
    #pragma unroll
    for (int i = 0; i < HH; ++i) w1c[i] = w1[i * HH + lane];
    #pragma unroll
    for (int i = 0; i < HH; ++i) w2c[i] = w2[i * HH + lane];
    const float b1j = b1[lane];
    const float b2j = b2[lane];
    const float epsv = 1.0f + epsp[0];

    float s1 = 0.0f, s2 = 0.0f;
    for (int n = wave; n < NN; n += nwaves) {
        const float z = fmaf(epsv, hin[n * HH + lane], agg[n * HH + lane]);
        float u = b1j;
        #pragma unroll
        for (int k = 0; k < HH; ++k) u = fmaf(bcastf(z, k), w1c[k], u);
        u = fmaxf(u, 0.0f);
        float v = b2j;
        #pragma unroll
        for (int k = 0; k < HH; ++k) v = fmaf(bcastf(u, k), w2c[k], v);
        v = fmaxf(v, 0.0f);
        agg[n * HH + lane] = v;
        s1 += v;
        s2 += v * v;
    }
    atomicAdd(&stats[lane], s1);
    atomicAdd(&stats[64 + lane], s2);
}

// ---------------------------------------------------------------------------
__global__ void bn_finalize(float* stats) {
    int j = threadIdx.x;
    if (j < HH) {
        float mu  = stats[j] * (1.0f / NN);
        float var = stats[64 + j] * (1.0f / NN) - mu * mu;
        stats[128 + j] = mu;
        stats[192 + j] = 1.0f / sqrtf(var + 1e-5f);
    }
}

// BN apply: h_new = (v-mu)*rsig*gamma+beta ; also accumulate graph pooling sums
__global__ void bn_apply(
    const float* __restrict__ v, const float* __restrict__ stats,
    const float* __restrict__ gamma, const float* __restrict__ beta,
    const int* __restrict__ batch,
    float* __restrict__ hout, float* __restrict__ pooled, int layer)
{
    int idx = blockIdx.x * blockDim.x + threadIdx.x;
    if (idx >= NN * HH) return;
    int j = idx & 63;
    int n = idx >> 6;
    float z = (v[idx] - stats[128 + j]) * stats[192 + j] * gamma[j] + beta[j];
    hout[idx] = z;
    atomicAdd(&pooled[batch[n] * (NL * HH) + layer * HH + j], z);
}

// ---------------------------------------------------------------------------
// Graph head: g = relu(mean_pool @ fc0 + b)*w ; s_acc[sgb[g]] += g
__global__ __launch_bounds__(256, 1) void graph_kernel(
    const float* __restrict__ pooled, const float* __restrict__ cnt,
    const float* __restrict__ fc0_w, const float* __restrict__ fc0_b,
    const float* __restrict__ wts, const int* __restrict__ sgb,
    float* __restrict__ s_acc)
{
    __shared__ float w[NL * HH * HH];   // 192x64 = 48KB
    for (int i = threadIdx.x; i < NL * HH * HH; i += blockDim.x) w[i] = fc0_w[i];
    __syncthreads();
    const int lane = threadIdx.x & 63;
    const int g = blockIdx.x * 4 + (threadIdx.x >> 6);
    if (g >= NG) return;
    const float inv = 1.0f / fmaxf(cnt[g], 1.0f);
    float acc = fc0_b[lane];
    #pragma unroll
    for (int c = 0; c < NL; ++c) {
        const float a = pooled[g * (NL * HH) + c * HH + lane] * inv;
        #pragma unroll
        for (int k = 0; k < HH; ++k)
            acc = fmaf(bcastf(a, k), w[(c * HH + k) * HH + lane], acc);
    }
    const float og = fmaxf(acc, 0.0f) * wts[g];
    atomicAdd(&s_acc[sgb[g] * HH + lane], og);
}

// Final head: s -> fc1 relu -> fc2 relu -> pred
__global__ __launch_bounds__(256, 1) void final_kernel(
    const float* __restrict__ s_acc, const float* __restrict__ norm,
    const float* __restrict__ fc1_w, const float* __restrict__ fc1_b,
    const float* __restrict__ fc2_w, const float* __restrict__ fc2_b,
    const float* __restrict__ pw, const float* __restrict__ pb,
    float* __restrict__ out)
{
    const int lane = threadIdx.x & 63;
    const int s = blockIdx.x * 4 + (threadIdx.x >> 6);
    if (s >= NSG) return;
    const float xv = s_acc[s * HH + lane] / fmaxf(norm[s], 1e-12f);
    float u = fc1_b[lane];
    #pragma unroll
    for (int k = 0; k < HH; ++k) u = fmaf(bcastf(xv, k), fc1_w[k * HH + lane], u);
    u = fmaxf(u, 0.0f);
    float v = fc2_b[lane];
    #pragma unroll
    for (int k = 0; k < HH; ++k) v = fmaf(bcastf(u, k), fc2_w[k * HH + lane], v);
    v = fmaxf(v, 0.0f);
    float o = pb[lane & 31];
    #pragma unroll
    for (int k = 0; k < HH; ++k) o = fmaf(bcastf(v, k), pw[k * NOUT + (lane & 31)], o);
    if (lane < NOUT) out[s * NOUT + lane] = o;
}

// ---------------------------------------------------------------------------
extern "C" void kernel_launch(void* const* d_in, const int* in_sizes, int n_in,
                              void* d_out, int out_size, void* d_ws, size_t ws_size,
                              hipStream_t stream)
{
    const float* x        = (const float*)d_in[0];
    const int*   eidx     = (const int*)d_in[1];
    const float* eattr    = (const float*)d_in[2];
    const int*   batch    = (const int*)d_in[3];
    const float* weights  = (const float*)d_in[4];
    const int*   sgb      = (const int*)d_in[5];
    const float* be_w1    = (const float*)d_in[6];
    const float* be_b1    = (const float*)d_in[7];
    const float* be_w2    = (const float*)d_in[8];
    const float* be_b2    = (const float*)d_in[9];
    const float* mlp_w1   = (const float*)d_in[10];
    const float* mlp_b1   = (const float*)d_in[11];
    const float* mlp_w2   = (const float*)d_in[12];
    const float* mlp_b2   = (const float*)d_in[13];
    const float* eps      = (const float*)d_in[14];
    const float* bn_gamma = (const float*)d_in[15];
    const float* bn_beta  = (const float*)d_in[16];
    const float* fc0_w    = (const float*)d_in[17];
    const float* fc0_b    = (const float*)d_in[18];
    const float* fc1_w    = (const float*)d_in[19];
    const float* fc1_b    = (const float*)d_in[20];
    const float* fc2_w    = (const float*)d_in[21];
    const float* fc2_b    = (const float*)d_in[22];
    const float* pred_w   = (const float*)d_in[23];
    const float* pred_b   = (const float*)d_in[24];
    float* out = (float*)d_out;

    float* ws     = (float*)d_ws;
    float* h_buf  = ws;                               // NN*64
    float* agg    = ws + (size_t)NN * HH;             // NN*64 (also holds v)
    float* pooled = ws + (size_t)NN * HH * 2;         // NG*192
    float* cnt    = pooled + (size_t)NG * NL * HH;    // NG
    float* stats  = cnt + NG;                         // 256
    float* s_acc  = stats + 256;                      // NSG*64
    float* norm   = s_acc + (size_t)NSG * HH;         // NSG

    // zero all accumulators used across the whole pass (contiguous block)
    size_t acc_floats = (size_t)NG * NL * HH + NG + 256 + (size_t)NSG * HH + NSG;
    hipMemsetAsync(pooled, 0, acc_floats * sizeof(float), stream);

    cnt_kernel<<<(NN + 255) / 256, 256, 0, stream>>>(batch, cnt);
    norm_kernel<<<4, 256, 0, stream>>>(sgb, weights, norm);

    const float* hin = x;
    for (int l = 0; l < NL; ++l) {
        hipMemsetAsync(agg, 0, (size_t)NN * HH * sizeof(float), stream);
        hipMemsetAsync(stats, 0, 256 * sizeof(float), stream);
        edge_kernel<<<2048, 256, 0, stream>>>(
            hin, eattr, eidx,
            be_w1 + l * EF * HH, be_b1 + l * HH,
            be_w2 + l * HH * HH, be_b2 + l * HH, agg);
        node_kernel<<<1024, 256, 0, stream>>>(
            hin, agg,
            mlp_w1 + l * HH * HH, mlp_b1 + l * HH,
            mlp_w2 + l * HH * HH, mlp_b2 + l * HH,
            eps + l, stats);
        bn_finalize<<<1, 64, 0, stream>>>(stats);
        bn_apply<<<(NN * HH + 255) / 256, 256, 0, stream>>>(
            agg, stats, bn_gamma + l * HH, bn_beta + l * HH,
            batch, h_buf, pooled, l);
        hin = h_buf;
    }

    graph_kernel<<<NG / 4, 256, 0, stream>>>(pooled, cnt, fc0_w, fc0_b,
                                             weights, sgb, s_acc);
    final_kernel<<<NSG / 4, 256, 0, stream>>>(s_acc, norm, fc1_w, fc1_b,
                                              fc2_w, fc2_b, pred_w, pred_b, out);
}